// Round 7
// baseline (472.528 us; speedup 1.0000x reference)
//
#include <hip/hip_runtime.h>
#include <hip/hip_bf16.h>

// Swin window MHSA, MI355X, round 7.
//   k_prep : Aext[2176x256]=G'(+w1/w2 rows), Wov3[256x2048], cvec, relL2(+c0)
//   k_conv : X fp32 -> rolled bf16 Xroll[n][3200][256]  (coalesced stores)
//   k_gemm1: M_T[t][a'] = Xroll . Aext^T  -- NO LDS: MFMA frags streamed from L2
//   k_attn2: per (n,window): S=Xp.M, softmax, T=X.wmap; T overwrites M in-place
//   k_gemm3: out[o][t] = Wov3 . T_T^T + cvec -- NO LDS, 128o x 64t tiles

#define NBATCH 8
#define MSTR   2176           // M_T / T_T row stride (a'-dim, 17 tiles of 128)
#define TROWS  3200           // padded token rows (25 tiles of 128)

typedef unsigned short ushort_t;
typedef __attribute__((ext_vector_type(8))) short bf16x8;   // 8 bf16 = 4 VGPR
typedef __attribute__((ext_vector_type(8))) unsigned short u16x8;
typedef __attribute__((ext_vector_type(4))) float f32x4;    // MFMA acc

__device__ __forceinline__ float b2f(ushort_t u) {
  union { unsigned int i; float f; } v; v.i = ((unsigned int)u) << 16; return v.f;
}
__device__ __forceinline__ ushort_t f2b(float f) {
  union { float f; unsigned int u; } v; v.f = f;
  unsigned int u = v.u;
  return (ushort_t)((u + 0x7FFFu + ((u >> 16) & 1u)) >> 16);
}
__device__ __forceinline__ int regof(int y) { return (y < 49) ? 0 : ((y < 53) ? 1 : 2); }
__device__ __forceinline__ int div7(int t) { return (t * 37) >> 8; }  // t/7, t<64
__device__ __forceinline__ int tmap(int p, int gi, int gj) {
  int wi = div7(p); return (gi * 7 + wi) * 56 + gj * 7 + (p - wi * 7);
}
__device__ __forceinline__ ushort4 pack4(f32x4 a) {
  ushort4 u; u.x = f2b(a[0]); u.y = f2b(a[1]); u.z = f2b(a[2]); u.w = f2b(a[3]);
  return u;
}

// ================= prep (unchanged) =================
__global__ void k_prep(const float* __restrict__ Wk, const float* __restrict__ Wq,
                       const float* __restrict__ Wo, const float* __restrict__ Wv,
                       const float* __restrict__ bk, const float* __restrict__ bq,
                       const float* __restrict__ bv, const float* __restrict__ bo,
                       const float* __restrict__ relc,
                       ushort_t* __restrict__ Aext, ushort_t* __restrict__ Wov3,
                       float* __restrict__ cvec, float* __restrict__ relL2) {
  __shared__ float red[8];
  int blk = blockIdx.x, t = threadIdx.x;
  if (blk < 512) {
    int h = blk >> 6, b0 = (blk & 63) << 2, a = t;
    const float* wkh = Wk + h * 65536;
    const float* wqh = Wq + h * 65536;
    float a0 = 0.f, a1 = 0.f, a2 = 0.f, a3 = 0.f;
    for (int dd = 0; dd < 256; ++dd) {
      float wk = wkh[dd * 256 + a];
      float4 w4 = *(const float4*)(wqh + dd * 256 + b0);
      a0 += wk * w4.x; a1 += wk * w4.y; a2 += wk * w4.z; a3 += wk * w4.w;
    }
    ushort4 u; u.x = f2b(a0); u.y = f2b(a1); u.z = f2b(a2); u.w = f2b(a3);
    *(ushort4*)(Aext + (h * 256 + a) * 256 + b0) = u;
  } else if (blk < 1024) {
    int bb = blk - 512;
    int h = bb >> 6, o0 = (bb & 63) << 2, d = t;
    float a0 = 0.f, a1 = 0.f, a2 = 0.f, a3 = 0.f;
    for (int dd = 0; dd < 256; ++dd) {
      float wv = Wv[(h * 256 + dd) * 256 + d];
      a0 += Wo[(o0 + 0) * 2048 + h * 256 + dd] * wv;
      a1 += Wo[(o0 + 1) * 2048 + h * 256 + dd] * wv;
      a2 += Wo[(o0 + 2) * 2048 + h * 256 + dd] * wv;
      a3 += Wo[(o0 + 3) * 2048 + h * 256 + dd] * wv;
    }
    Wov3[(o0 + 0) * 2048 + h * 256 + d] = f2b(a0);
    Wov3[(o0 + 1) * 2048 + h * 256 + d] = f2b(a1);
    Wov3[(o0 + 2) * 2048 + h * 256 + d] = f2b(a2);
    Wov3[(o0 + 3) * 2048 + h * 256 + d] = f2b(a3);
  } else if (blk < 1032) {
    int h = blk - 1024;
    float s1 = 0.f, s2 = 0.f;
    for (int dd = 0; dd < 256; ++dd) {
      s1 += bk[h * 256 + dd] * Wq[(h * 256 + dd) * 256 + t];
      s2 += bq[h * 256 + dd] * Wk[(h * 256 + dd) * 256 + t];
    }
    Aext[(2048 + h) * 256 + t] = f2b(s1);
    Aext[(2056 + h) * 256 + t] = f2b(s2);
  } else if (blk == 1032) {
    for (int i = t; i < 112 * 256 / 8; i += 256)
      *(u16x8*)(Aext + 2064 * 256 + i * 8) = (u16x8){0,0,0,0,0,0,0,0};
  } else if (blk < 1289) {
    int o = blk - 1033;
    const float* wob = Wo + o * 2048;
    float acc = 0.f;
#pragma unroll
    for (int j = 0; j < 8; ++j) acc += wob[j * 256 + t] * bv[j * 256 + t];
#pragma unroll
    for (int s = 1; s < 64; s <<= 1) acc += __shfl_xor(acc, s);
    if ((t & 63) == 0) red[t >> 6] = acc;
    __syncthreads();
    if (t == 0) cvec[o] = bo[o] + red[0] + red[1] + red[2] + red[3];
  } else {
    if (t < 8) {
      float c = 0.f;
      for (int dd = 0; dd < 256; ++dd) c += bk[t * 256 + dd] * bq[t * 256 + dd];
      red[t] = c * 0.0625f;
    }
    __syncthreads();
    for (int i = t; i < 8 * 169; i += 256) {
      int h = i / 169, idx = i - h * 169;
      relL2[i] = relc[idx * 8 + h] + red[h];
    }
  }
}

// ================= conv (unchanged) =================
__global__ void k_conv(const float* __restrict__ X, ushort_t* __restrict__ Xroll) {
  const int n = blockIdx.x / 57, y = blockIdx.x % 57;
  ushort_t* xr = Xroll + (size_t)n * TROWS * 256;
  const int d = threadIdx.x;
  if (y == 56) {
    for (int i = d; i < 64 * 256 / 8; i += 256)
      *(u16x8*)(xr + 3136 * 256 + i * 8) = (u16x8){0,0,0,0,0,0,0,0};
    return;
  }
  const int c = d >> 4, p1 = (d >> 2) & 3, p2 = d & 3;
  const int sp = c * 16 + (((p1 + 1) & 3) << 2) + ((p2 + 1) & 3);
  const int ty = (p1 == 3) ? y : ((y == 0) ? 55 : y - 1);
  const float* rowp = X + (size_t)n * 256 * 3136 + sp * 3136 + ty * 56;
  ushort_t* orow = xr + y * 56 * 256 + d;
  for (int x = 0; x < 56; ++x) {
    int tx = (p2 == 3) ? x : ((x == 0) ? 55 : x - 1);
    orow[x * 256] = f2b(rowp[tx]);
  }
}

// ================= gemm1: M_T[t][a'] = Xroll . Aext^T, NO LDS =============
// MFMA fragments loaded straight from global (L2-hot): each 64-lane frag load
// covers 16 rows x 64B = 16 full cache lines. Zero barriers, zero LDS.
__global__ __launch_bounds__(256, 3) void k_gemm1(
    const ushort_t* __restrict__ Xroll, const ushort_t* __restrict__ Aext,
    ushort_t* __restrict__ MT) {
  const int bx = blockIdx.x;
  const int n = bx / 425, r = bx % 425;
  const int tt = r / 17, aa = r % 17;
  const int a0 = aa * 128, t0 = tt * 128;
  const int tid = threadIdx.x, wave = tid >> 6, lane = tid & 63;
  const int quad = lane >> 4, l16 = lane & 15;
  const int wa = wave >> 1, wt = wave & 1;
  const ushort_t* Xn = Xroll + (size_t)n * TROWS * 256;
  ushort_t* Mn = MT + (size_t)n * TROWS * MSTR;

  const ushort_t* ab = Aext + (a0 + wa * 64 + l16) * 256 + quad * 8;
  const ushort_t* bb = Xn + (size_t)(t0 + wt * 64 + l16) * 256 + quad * 8;

  f32x4 acc[4][4];
#pragma unroll
  for (int i = 0; i < 4; ++i)
#pragma unroll
    for (int j = 0; j < 4; ++j) acc[i][j] = (f32x4){0.f, 0.f, 0.f, 0.f};

  bf16x8 af[4], bf[4], afn[4], bfn[4];
#pragma unroll
  for (int i = 0; i < 4; ++i) {
    af[i] = *(const bf16x8*)(ab + i * 16 * 256);
    bf[i] = *(const bf16x8*)(bb + i * 16 * 256);
  }
#pragma unroll
  for (int kk = 0; kk < 8; ++kk) {
    if (kk < 7) {
#pragma unroll
      for (int i = 0; i < 4; ++i) {
        afn[i] = *(const bf16x8*)(ab + i * 16 * 256 + (kk + 1) * 32);
        bfn[i] = *(const bf16x8*)(bb + i * 16 * 256 + (kk + 1) * 32);
      }
    }
#pragma unroll
    for (int i = 0; i < 4; ++i)
#pragma unroll
      for (int j = 0; j < 4; ++j)
        acc[i][j] = __builtin_amdgcn_mfma_f32_16x16x32_bf16(af[i], bf[j], acc[i][j], 0, 0, 0);
    if (kk < 7) {
#pragma unroll
      for (int i = 0; i < 4; ++i) { af[i] = afn[i]; bf[i] = bfn[i]; }
    }
  }
  // store C transposed: M_T[t][a']
#pragma unroll
  for (int i = 0; i < 4; ++i)
#pragma unroll
    for (int j = 0; j < 4; ++j) {
      int tg = t0 + wt * 64 + j * 16 + l16;
      int ag = a0 + wa * 64 + i * 16 + quad * 4;
      *(ushort4*)(Mn + (size_t)tg * MSTR + ag) = pack4(acc[i][j]);
    }
}

// ================= attn2 (unchanged) ==============================
#define XP_STR 264
__global__ __launch_bounds__(512, 4) void k_attn2(
    const ushort_t* __restrict__ Xroll, ushort_t* __restrict__ MT,
    const float* __restrict__ relL2) {
  __shared__ ushort_t Xp[64 * XP_STR];
  __shared__ ushort_t StB[2][64 * 72];
  __shared__ float aqsL[8 * 64];
  __shared__ float bpsL[8 * 64];
  __shared__ float relLh[8 * 169];

  const int tid = threadIdx.x;
  const int wave = tid >> 6, lane = tid & 63;
  const int quad = lane >> 4, l16 = lane & 15;
  const int group = wave >> 2, wv = wave & 3;
  const int n = blockIdx.x >> 6, g = blockIdx.x & 63;
  const int gi = g >> 3, gj = g & 7;
  const ushort_t* Xn = Xroll + (size_t)n * TROWS * 256;
  ushort_t* Mn = MT + (size_t)n * TROWS * MSTR;

  {
    const int p = tid & 63, cg = tid >> 6;
    if (p < 49) {
      int t = tmap(p, gi, gj);
#pragma unroll
      for (int i = 0; i < 4; ++i)
        *(u16x8*)(&Xp[p * XP_STR + (cg * 4 + i) * 8]) =
            *(const u16x8*)(Xn + t * 256 + (cg * 4 + i) * 8);
    } else {
#pragma unroll
      for (int i = 0; i < 4; ++i)
        *(u16x8*)(&Xp[p * XP_STR + (cg * 4 + i) * 8]) = (u16x8){0,0,0,0,0,0,0,0};
    }
  }
  for (int i = tid; i < 8 * 169; i += 512) relLh[i] = relL2[i];
  {
    const int h = tid >> 6, q = tid & 63;
    int qq = (q < 49) ? q : 48;
    int t = tmap(qq, gi, gj);
    aqsL[h * 64 + q] = b2f(Mn[(size_t)t * MSTR + 2048 + h]);
    bpsL[h * 64 + q] = b2f(Mn[(size_t)t * MSTR + 2056 + h]);
  }
  __syncthreads();

  bf16x8 xfr[4][2];
#pragma unroll
  for (int dt = 0; dt < 4; ++dt) {
    const int d = (wv * 4 + dt) * 16 + l16;
#pragma unroll
    for (int kk = 0; kk < 2; ++kk)
#pragma unroll
      for (int j = 0; j < 8; ++j)
        xfr[dt][kk][j] = (short)Xp[(kk * 32 + quad * 8 + j) * XP_STR + d];
  }

  const int q = wv * 16 + l16;
  const int qq = (q < 49) ? q : 48;
  const int tq = tmap(qq, gi, gj);
  const ushort_t* Mbase = Mn + (size_t)tq * MSTR + quad * 8;
  const int yq = div7(qq), xq = qq - yq * 7;
  const int fq = regof(gi * 7 + yq) * 3 + regof(gj * 7 + xq);

  for (int hh = 0; hh < 4; ++hh) {
    const int h = hh * 2 + group;
    f32x4 sacc[4];
#pragma unroll
    for (int pt = 0; pt < 4; ++pt) sacc[pt] = (f32x4){0.f, 0.f, 0.f, 0.f};
    const ushort_t* mrow = Mbase + h * 256;
#pragma unroll
    for (int kk = 0; kk < 8; ++kk) {
      bf16x8 bfm = *(const bf16x8*)(mrow + kk * 32);
#pragma unroll
      for (int pt = 0; pt < 4; ++pt) {
        bf16x8 af = *(const bf16x8*)(&Xp[(pt * 16 + l16) * XP_STR + kk * 32 + quad * 8]);
        sacc[pt] = __builtin_amdgcn_mfma_f32_16x16x32_bf16(af, bfm, sacc[pt], 0, 0, 0);
      }
    }
    float v[16];
    const float aqv = aqsL[h * 64 + q];
    const float* rel_h = &relLh[h * 169];
    float m = -1e30f;
#pragma unroll
    for (int pt = 0; pt < 4; ++pt)
#pragma unroll
      for (int r = 0; r < 4; ++r) {
        int p = pt * 16 + quad * 4 + r;
        float val = -1e30f;
        if (p < 49) {
          int yp = div7(p), xp = p - yp * 7;
          int fp = regof(gi * 7 + yp) * 3 + regof(gj * 7 + xp);
          val = (sacc[pt][r] + aqv + bpsL[h * 64 + p]) * 0.0625f +
                rel_h[(yp - yq + 6) + 13 * (xp - xq + 6)];
          if (fp != fq) val -= 100.f;
        }
        v[pt * 4 + r] = val;
        m = fmaxf(m, val);
      }
    m = fmaxf(m, __shfl_xor(m, 16));
    m = fmaxf(m, __shfl_xor(m, 32));
    float s = 0.f;
#pragma unroll
    for (int i = 0; i < 16; ++i) { v[i] = __expf(v[i] - m); s += v[i]; }
    s += __shfl_xor(s, 16);
    s += __shfl_xor(s, 32);
    const float inv = 1.f / s;
    __syncthreads();
    {
      ushort_t* sb = &StB[group][q * 72];
#pragma unroll
      for (int pt = 0; pt < 4; ++pt) {
        ushort4 u;
        u.x = f2b(v[pt * 4 + 0] * inv); u.y = f2b(v[pt * 4 + 1] * inv);
        u.z = f2b(v[pt * 4 + 2] * inv); u.w = f2b(v[pt * 4 + 3] * inv);
        *(ushort4*)(&sb[pt * 16 + quad * 4]) = u;
      }
    }
    __syncthreads();
#pragma unroll
    for (int qt = 0; qt < 4; ++qt) {
      f32x4 tacc[4];
#pragma unroll
      for (int dt = 0; dt < 4; ++dt) tacc[dt] = (f32x4){0.f, 0.f, 0.f, 0.f};
#pragma unroll
      for (int kk = 0; kk < 2; ++kk) {
        bf16x8 bfw = *(const bf16x8*)(&StB[group][(qt * 16 + l16) * 72 + kk * 32 + quad * 8]);
#pragma unroll
        for (int dt = 0; dt < 4; ++dt)
          tacc[dt] = __builtin_amdgcn_mfma_f32_16x16x32_bf16(xfr[dt][kk], bfw, tacc[dt], 0, 0, 0);
      }
      int q2 = qt * 16 + l16;
      if (q2 < 49) {
        int t2 = tmap(q2, gi, gj);
#pragma unroll
        for (int dt = 0; dt < 4; ++dt) {
          int d0 = (wv * 4 + dt) * 16 + quad * 4;
          *(ushort4*)(Mn + (size_t)t2 * MSTR + h * 256 + d0) = pack4(tacc[dt]);
        }
      }
    }
  }
}

// ================= gemm3: out[o][t] = Wov3 . T_T^T + cvec, NO LDS =========
// 128o x 64t tiles, t-tiles of 64 -> exactly 49 per batch row-block (no pad).
__global__ __launch_bounds__(256, 4) void k_gemm3(
    const ushort_t* __restrict__ Wov3, const ushort_t* __restrict__ MT,
    const float* __restrict__ cvec, float* __restrict__ out) {
  const int bx = blockIdx.x;
  const int n = bx / 98, r2 = bx % 98;
  const int oi = r2 / 49, tt = r2 % 49;
  const int o0 = oi * 128, t0 = tt * 64;
  const int tid = threadIdx.x, wave = tid >> 6, lane = tid & 63;
  const int quad = lane >> 4, l16 = lane & 15;
  const ushort_t* Tn = MT + (size_t)n * TROWS * MSTR;
  float* on = out + (size_t)n * 256 * 3136;

  const ushort_t* ab = Wov3 + (o0 + wave * 32 + l16) * 2048 + quad * 8;
  const ushort_t* bb = Tn + (size_t)(t0 + l16) * MSTR + quad * 8;

  f32x4 acc[2][4];
#pragma unroll
  for (int i = 0; i < 2; ++i)
#pragma unroll
    for (int j = 0; j < 4; ++j) acc[i][j] = (f32x4){0.f, 0.f, 0.f, 0.f};

  bf16x8 af[2], bf[4], afn[2], bfn[4];
#pragma unroll
  for (int i = 0; i < 2; ++i) af[i] = *(const bf16x8*)(ab + i * 16 * 2048);
#pragma unroll
  for (int j = 0; j < 4; ++j) bf[j] = *(const bf16x8*)(bb + (size_t)(j * 16) * MSTR);

  for (int kk = 0; kk < 64; ++kk) {
    if (kk < 63) {
      const int ko = (kk + 1) * 32;
#pragma unroll
      for (int i = 0; i < 2; ++i)
        afn[i] = *(const bf16x8*)(ab + i * 16 * 2048 + ko);
#pragma unroll
      for (int j = 0; j < 4; ++j)
        bfn[j] = *(const bf16x8*)(bb + (size_t)(j * 16) * MSTR + ko);
    }
#pragma unroll
    for (int i = 0; i < 2; ++i)
#pragma unroll
      for (int j = 0; j < 4; ++j)
        acc[i][j] = __builtin_amdgcn_mfma_f32_16x16x32_bf16(af[i], bf[j], acc[i][j], 0, 0, 0);
    if (kk < 63) {
#pragma unroll
      for (int i = 0; i < 2; ++i) af[i] = afn[i];
#pragma unroll
      for (int j = 0; j < 4; ++j) bf[j] = bfn[j];
    }
  }
  // epilogue: + cvec, coalesced fp32 stores (l16 contiguous in t)
#pragma unroll
  for (int i = 0; i < 2; ++i) {
    const int ob = o0 + wave * 32 + i * 16 + quad * 4;
    const float4 cv = *(const float4*)(cvec + ob);
#pragma unroll
    for (int j = 0; j < 4; ++j) {
      const int tg = t0 + j * 16 + l16;
      on[(size_t)(ob + 0) * 3136 + tg] = acc[i][j][0] + cv.x;
      on[(size_t)(ob + 1) * 3136 + tg] = acc[i][j][1] + cv.y;
      on[(size_t)(ob + 2) * 3136 + tg] = acc[i][j][2] + cv.z;
      on[(size_t)(ob + 3) * 3136 + tg] = acc[i][j][3] + cv.w;
    }
  }
}

extern "C" void kernel_launch(void* const* d_in, const int* in_sizes, int n_in,
                              void* d_out, int out_size, void* d_ws, size_t ws_size,
                              hipStream_t stream) {
  (void)in_sizes; (void)n_in; (void)out_size; (void)ws_size;
  const float* X  = (const float*)d_in[0];
  const float* Wk = (const float*)d_in[1];
  const float* bk = (const float*)d_in[2];
  const float* Wq = (const float*)d_in[3];
  const float* bq = (const float*)d_in[4];
  const float* Wv = (const float*)d_in[5];
  const float* bv = (const float*)d_in[6];
  const float* Wo = (const float*)d_in[7];
  const float* bo = (const float*)d_in[8];
  const float* rc = (const float*)d_in[9];

  ushort_t* MT    = (ushort_t*)d_ws;                       // 8*3200*2176 u16
  ushort_t* Xroll = MT + (size_t)8 * TROWS * MSTR;         // 8*3200*256 u16
  ushort_t* Aext  = Xroll + (size_t)8 * TROWS * 256;       // 2176*256 u16
  ushort_t* Wov3  = Aext + 2176 * 256;                     // 256*2048 u16
  float* fbase = (float*)(Wov3 + 256 * 2048);
  float* cvec  = fbase;         // 256 f32
  float* relL2 = fbase + 256;   // 8*169 f32
  float* out = (float*)d_out;

  k_prep <<<dim3(1290), dim3(256), 0, stream>>>(Wk, Wq, Wo, Wv, bk, bq, bv, bo, rc,
                                                Aext, Wov3, cvec, relL2);
  k_conv <<<dim3(8 * 57), dim3(256), 0, stream>>>(X, Xroll);
  k_gemm1<<<dim3(8 * 425), dim3(256), 0, stream>>>(Xroll, Aext, MT);
  k_attn2<<<dim3(8 * 64), dim3(512), 0, stream>>>(Xroll, MT, relL2);
  k_gemm3<<<dim3(8 * 98), dim3(256), 0, stream>>>(Wov3, MT, cvec, out);
}

// Round 8
// 365.897 us; speedup vs baseline: 1.2914x; 1.2914x over previous
//
#include <hip/hip_runtime.h>
#include <hip/hip_bf16.h>

// Swin window MHSA, MI355X, round 8.
//   k_prep : Aext[2176x256]=G'(+w1/w2 rows), Wov3[256x2048], cvec, relL2(+c0)
//   k_conv : X fp32 -> rolled bf16 Xroll[n][3200][256]
//   k_gemm1: M_T[t][a'] = Xroll . Aext^T  (R5 register-staged, 4 blocks/CU)
//   k_attn3: per (n,window): S=Xp.M -> softmax -> T=X.wmap (LDS) -> Y+=Wov.T
//            fused epilogue writes out directly; T never touches HBM.

#define NBATCH 8
#define MSTR   2176           // M_T row stride (a'-dim)
#define TROWS  3200           // padded token rows

typedef unsigned short ushort_t;
typedef __attribute__((ext_vector_type(8))) short bf16x8;   // 8 bf16 = 4 VGPR
typedef __attribute__((ext_vector_type(8))) unsigned short u16x8;
typedef __attribute__((ext_vector_type(4))) float f32x4;    // MFMA acc

__device__ __forceinline__ float b2f(ushort_t u) {
  union { unsigned int i; float f; } v; v.i = ((unsigned int)u) << 16; return v.f;
}
__device__ __forceinline__ ushort_t f2b(float f) {
  union { float f; unsigned int u; } v; v.f = f;
  unsigned int u = v.u;
  return (ushort_t)((u + 0x7FFFu + ((u >> 16) & 1u)) >> 16);
}
__device__ __forceinline__ int regof(int y) { return (y < 49) ? 0 : ((y < 53) ? 1 : 2); }
__device__ __forceinline__ int div7(int t) { return (t * 37) >> 8; }  // t/7, t<64
__device__ __forceinline__ int tmap(int p, int gi, int gj) {
  int wi = div7(p); return (gi * 7 + wi) * 56 + gj * 7 + (p - wi * 7);
}
__device__ __forceinline__ ushort4 pack4(f32x4 a) {
  ushort4 u; u.x = f2b(a[0]); u.y = f2b(a[1]); u.z = f2b(a[2]); u.w = f2b(a[3]);
  return u;
}

// ================= prep (unchanged) =================
__global__ void k_prep(const float* __restrict__ Wk, const float* __restrict__ Wq,
                       const float* __restrict__ Wo, const float* __restrict__ Wv,
                       const float* __restrict__ bk, const float* __restrict__ bq,
                       const float* __restrict__ bv, const float* __restrict__ bo,
                       const float* __restrict__ relc,
                       ushort_t* __restrict__ Aext, ushort_t* __restrict__ Wov3,
                       float* __restrict__ cvec, float* __restrict__ relL2) {
  __shared__ float red[8];
  int blk = blockIdx.x, t = threadIdx.x;
  if (blk < 512) {
    int h = blk >> 6, b0 = (blk & 63) << 2, a = t;
    const float* wkh = Wk + h * 65536;
    const float* wqh = Wq + h * 65536;
    float a0 = 0.f, a1 = 0.f, a2 = 0.f, a3 = 0.f;
    for (int dd = 0; dd < 256; ++dd) {
      float wk = wkh[dd * 256 + a];
      float4 w4 = *(const float4*)(wqh + dd * 256 + b0);
      a0 += wk * w4.x; a1 += wk * w4.y; a2 += wk * w4.z; a3 += wk * w4.w;
    }
    ushort4 u; u.x = f2b(a0); u.y = f2b(a1); u.z = f2b(a2); u.w = f2b(a3);
    *(ushort4*)(Aext + (h * 256 + a) * 256 + b0) = u;
  } else if (blk < 1024) {
    int bb = blk - 512;
    int h = bb >> 6, o0 = (bb & 63) << 2, d = t;
    float a0 = 0.f, a1 = 0.f, a2 = 0.f, a3 = 0.f;
    for (int dd = 0; dd < 256; ++dd) {
      float wv = Wv[(h * 256 + dd) * 256 + d];
      a0 += Wo[(o0 + 0) * 2048 + h * 256 + dd] * wv;
      a1 += Wo[(o0 + 1) * 2048 + h * 256 + dd] * wv;
      a2 += Wo[(o0 + 2) * 2048 + h * 256 + dd] * wv;
      a3 += Wo[(o0 + 3) * 2048 + h * 256 + dd] * wv;
    }
    Wov3[(o0 + 0) * 2048 + h * 256 + d] = f2b(a0);
    Wov3[(o0 + 1) * 2048 + h * 256 + d] = f2b(a1);
    Wov3[(o0 + 2) * 2048 + h * 256 + d] = f2b(a2);
    Wov3[(o0 + 3) * 2048 + h * 256 + d] = f2b(a3);
  } else if (blk < 1032) {
    int h = blk - 1024;
    float s1 = 0.f, s2 = 0.f;
    for (int dd = 0; dd < 256; ++dd) {
      s1 += bk[h * 256 + dd] * Wq[(h * 256 + dd) * 256 + t];
      s2 += bq[h * 256 + dd] * Wk[(h * 256 + dd) * 256 + t];
    }
    Aext[(2048 + h) * 256 + t] = f2b(s1);
    Aext[(2056 + h) * 256 + t] = f2b(s2);
  } else if (blk == 1032) {
    for (int i = t; i < 112 * 256 / 8; i += 256)
      *(u16x8*)(Aext + 2064 * 256 + i * 8) = (u16x8){0,0,0,0,0,0,0,0};
  } else if (blk < 1289) {
    int o = blk - 1033;
    const float* wob = Wo + o * 2048;
    float acc = 0.f;
#pragma unroll
    for (int j = 0; j < 8; ++j) acc += wob[j * 256 + t] * bv[j * 256 + t];
#pragma unroll
    for (int s = 1; s < 64; s <<= 1) acc += __shfl_xor(acc, s);
    if ((t & 63) == 0) red[t >> 6] = acc;
    __syncthreads();
    if (t == 0) cvec[o] = bo[o] + red[0] + red[1] + red[2] + red[3];
  } else {
    if (t < 8) {
      float c = 0.f;
      for (int dd = 0; dd < 256; ++dd) c += bk[t * 256 + dd] * bq[t * 256 + dd];
      red[t] = c * 0.0625f;
    }
    __syncthreads();
    for (int i = t; i < 8 * 169; i += 256) {
      int h = i / 169, idx = i - h * 169;
      relL2[i] = relc[idx * 8 + h] + red[h];
    }
  }
}

// ================= conv (unchanged) =================
__global__ void k_conv(const float* __restrict__ X, ushort_t* __restrict__ Xroll) {
  const int n = blockIdx.x / 57, y = blockIdx.x % 57;
  ushort_t* xr = Xroll + (size_t)n * TROWS * 256;
  const int d = threadIdx.x;
  if (y == 56) {
    for (int i = d; i < 64 * 256 / 8; i += 256)
      *(u16x8*)(xr + 3136 * 256 + i * 8) = (u16x8){0,0,0,0,0,0,0,0};
    return;
  }
  const int c = d >> 4, p1 = (d >> 2) & 3, p2 = d & 3;
  const int sp = c * 16 + (((p1 + 1) & 3) << 2) + ((p2 + 1) & 3);
  const int ty = (p1 == 3) ? y : ((y == 0) ? 55 : y - 1);
  const float* rowp = X + (size_t)n * 256 * 3136 + sp * 3136 + ty * 56;
  ushort_t* orow = xr + y * 56 * 256 + d;
  for (int x = 0; x < 56; ++x) {
    int tx = (p2 == 3) ? x : ((x == 0) ? 55 : x - 1);
    orow[x * 256] = f2b(rowp[tx]);
  }
}

// ================= gemm1: R5 register-staged, occupancy 4 =================
__global__ __launch_bounds__(256, 4) void k_gemm1(
    const ushort_t* __restrict__ Xroll, const ushort_t* __restrict__ Aext,
    ushort_t* __restrict__ MT) {
  __shared__ ushort_t Asm[128 * 72];
  __shared__ ushort_t Bsm[128 * 72];
  const int bx = blockIdx.x;
  const int n = bx / 425, r = bx % 425;
  const int tt = r / 17, aa = r % 17;
  const int a0 = aa * 128, t0 = tt * 128;
  const int tid = threadIdx.x, wave = tid >> 6, lane = tid & 63;
  const int quad = lane >> 4, l16 = lane & 15;
  const int wa = wave >> 1, wt = wave & 1;
  const ushort_t* Xn = Xroll + (size_t)n * TROWS * 256;
  ushort_t* Mn = MT + (size_t)n * TROWS * MSTR;

  const int sr = tid >> 1, sc = (tid & 1) * 4;
  bf16x8 ra[4], rb[4];
#pragma unroll
  for (int i = 0; i < 4; ++i) {
    ra[i] = *(const bf16x8*)(Aext + (a0 + sr) * 256 + (sc + i) * 8);
    rb[i] = *(const bf16x8*)(Xn + (t0 + sr) * 256 + (sc + i) * 8);
  }

  f32x4 acc[4][4];
#pragma unroll
  for (int i = 0; i < 4; ++i)
#pragma unroll
    for (int j = 0; j < 4; ++j) acc[i][j] = (f32x4){0.f, 0.f, 0.f, 0.f};

  for (int kit = 0; kit < 4; ++kit) {
#pragma unroll
    for (int i = 0; i < 4; ++i) {
      *(bf16x8*)(&Asm[sr * 72 + (sc + i) * 8]) = ra[i];
      *(bf16x8*)(&Bsm[sr * 72 + (sc + i) * 8]) = rb[i];
    }
    __syncthreads();
    if (kit < 3) {
      int k0 = (kit + 1) * 64;
#pragma unroll
      for (int i = 0; i < 4; ++i) {
        ra[i] = *(const bf16x8*)(Aext + (a0 + sr) * 256 + k0 + (sc + i) * 8);
        rb[i] = *(const bf16x8*)(Xn + (t0 + sr) * 256 + k0 + (sc + i) * 8);
      }
    }
#pragma unroll
    for (int kk = 0; kk < 2; ++kk) {
      bf16x8 af[4], bf[4];
#pragma unroll
      for (int i = 0; i < 4; ++i)
        af[i] = *(const bf16x8*)(&Asm[(wa * 64 + i * 16 + l16) * 72 + kk * 32 + quad * 8]);
#pragma unroll
      for (int j = 0; j < 4; ++j)
        bf[j] = *(const bf16x8*)(&Bsm[(wt * 64 + j * 16 + l16) * 72 + kk * 32 + quad * 8]);
#pragma unroll
      for (int i = 0; i < 4; ++i)
#pragma unroll
        for (int j = 0; j < 4; ++j)
          acc[i][j] = __builtin_amdgcn_mfma_f32_16x16x32_bf16(af[i], bf[j], acc[i][j], 0, 0, 0);
    }
    __syncthreads();
  }
#pragma unroll
  for (int i = 0; i < 4; ++i)
#pragma unroll
    for (int j = 0; j < 4; ++j) {
      int tg = t0 + wt * 64 + j * 16 + l16;
      int ag = a0 + wa * 64 + i * 16 + quad * 4;
      *(ushort4*)(Mn + (size_t)tg * MSTR + ag) = pack4(acc[i][j]);
    }
}

// ================= attn3: S -> softmax -> T (LDS) -> Y+=Wov.T =============
#define XP3 264
__global__ __launch_bounds__(512, 4) void k_attn3(
    const ushort_t* __restrict__ Xroll, const ushort_t* __restrict__ MT,
    const ushort_t* __restrict__ Wov3, const float* __restrict__ relL2,
    const float* __restrict__ cvec, float* __restrict__ out) {
  __shared__ ushort_t Xp[64 * XP3];     // [p][d]      33792 B
  __shared__ ushort_t TT[64 * XP3];     // [q][d]      33792 B
  __shared__ ushort_t StB[64 * 72];     // [q][p]       9216 B
  __shared__ float aqsL[8 * 64];        //              2048 B
  __shared__ float bpsL[8 * 64];        //              2048 B  -> 80896 total

  const int tid = threadIdx.x;
  const int wave = tid >> 6, lane = tid & 63;
  const int quad = lane >> 4, l16 = lane & 15;
  const int n = blockIdx.x >> 6, g = blockIdx.x & 63;
  const int gi = g >> 3, gj = g & 7;
  const ushort_t* Xn = Xroll + (size_t)n * TROWS * 256;
  const ushort_t* Mn = MT + (size_t)n * TROWS * MSTR;

  // ---- prologue: Xp gather; all-head aq/bp ----
  {
    const int p = tid & 63, cg = tid >> 6;
    if (p < 49) {
      int t = tmap(p, gi, gj);
#pragma unroll
      for (int i = 0; i < 4; ++i)
        *(u16x8*)(&Xp[p * XP3 + (cg * 4 + i) * 8]) =
            *(const u16x8*)(Xn + t * 256 + (cg * 4 + i) * 8);
    } else {
#pragma unroll
      for (int i = 0; i < 4; ++i)
        *(u16x8*)(&Xp[p * XP3 + (cg * 4 + i) * 8]) = (u16x8){0,0,0,0,0,0,0,0};
    }
  }
  {
    const int h = tid >> 6, q = tid & 63;
    int qq = (q < 49) ? q : 48;
    int t = tmap(qq, gi, gj);
    aqsL[h * 64 + q] = b2f(Mn[(size_t)t * MSTR + 2048 + h]);
    bpsL[h * 64 + q] = b2f(Mn[(size_t)t * MSTR + 2056 + h]);
  }
  __syncthreads();

  // phase-T A-frags: X^T[d][p], d-tiles {2*wave, 2*wave+1}, in registers
  bf16x8 xfr[2][2];
#pragma unroll
  for (int i = 0; i < 2; ++i) {
    const int d = (wave * 2 + i) * 16 + l16;
#pragma unroll
    for (int kk = 0; kk < 2; ++kk)
#pragma unroll
      for (int j = 0; j < 8; ++j)
        xfr[i][kk][j] = (short)Xp[(kk * 32 + quad * 8 + j) * XP3 + d];
  }

  // S-phase wave mapping
  const int qt = wave >> 1, ph = wave & 1;
  const int q = qt * 16 + l16;
  const int qq = (q < 49) ? q : 48;
  const int tq = tmap(qq, gi, gj);
  const ushort_t* Mbase = Mn + (size_t)tq * MSTR + quad * 8;
  const int yq = div7(qq), xq = qq - yq * 7;
  const int fq = regof(gi * 7 + yq) * 3 + regof(gj * 7 + xq);

  f32x4 yac[2][4];
#pragma unroll
  for (int i = 0; i < 2; ++i)
#pragma unroll
    for (int j = 0; j < 4; ++j) yac[i][j] = (f32x4){0.f, 0.f, 0.f, 0.f};

  for (int h = 0; h < 8; ++h) {
    // ---- S: A = Xp (2 p-tiles), B = M row for q (global) ----
    f32x4 sacc[2];
#pragma unroll
    for (int i = 0; i < 2; ++i) sacc[i] = (f32x4){0.f, 0.f, 0.f, 0.f};
    const ushort_t* mrow = Mbase + h * 256;
#pragma unroll
    for (int kk = 0; kk < 8; ++kk) {
      bf16x8 bm = *(const bf16x8*)(mrow + kk * 32);
#pragma unroll
      for (int i = 0; i < 2; ++i) {
        bf16x8 af = *(const bf16x8*)(&Xp[((ph * 2 + i) * 16 + l16) * XP3 + kk * 32 + quad * 8]);
        sacc[i] = __builtin_amdgcn_mfma_f32_16x16x32_bf16(af, bm, sacc[i], 0, 0, 0);
      }
    }
    // bias + rel + mask -> StB[q][p] bf16
    {
      const float aqv = aqsL[h * 64 + q];
      const float* relh = relL2 + h * 169;
#pragma unroll
      for (int i = 0; i < 2; ++i) {
        ushort4 sv;
        ushort_t* svp = &sv.x;
#pragma unroll
        for (int r = 0; r < 4; ++r) {
          int p = (ph * 2 + i) * 16 + quad * 4 + r;
          float val = -1e30f;
          if (p < 49) {
            int yp = div7(p), xp = p - yp * 7;
            int fp = regof(gi * 7 + yp) * 3 + regof(gj * 7 + xp);
            val = (sacc[i][r] + aqv + bpsL[h * 64 + p]) * 0.0625f +
                  relh[(yp - yq + 6) + 13 * (xp - xq + 6)];
            if (fp != fq) val -= 100.f;
          }
          svp[r] = f2b(val);
        }
        *(ushort4*)(&StB[q * 72 + (ph * 2 + i) * 16 + quad * 4]) = sv;
      }
    }
    __syncthreads();  // b1: StB scores complete

    // ---- softmax over p per row q, in-place bf16 ----
    {
      const int sq = tid >> 3, sub = tid & 7;
      ushort_t* row = &StB[sq * 72 + sub * 8];
      bf16x8 in8 = *(const bf16x8*)row;
      float v[8];
#pragma unroll
      for (int i = 0; i < 8; ++i) v[i] = b2f((ushort_t)in8[i]);
      float m = v[0];
#pragma unroll
      for (int i = 1; i < 8; ++i) m = fmaxf(m, v[i]);
      m = fmaxf(m, __shfl_xor(m, 1));
      m = fmaxf(m, __shfl_xor(m, 2));
      m = fmaxf(m, __shfl_xor(m, 4));
      float s = 0.f;
#pragma unroll
      for (int i = 0; i < 8; ++i) { v[i] = __expf(v[i] - m); s += v[i]; }
      s += __shfl_xor(s, 1);
      s += __shfl_xor(s, 2);
      s += __shfl_xor(s, 4);
      float inv = 1.f / s;
      bf16x8 w8;
#pragma unroll
      for (int i = 0; i < 8; ++i) w8[i] = (short)f2b(v[i] * inv);
      *(bf16x8*)row = w8;
    }
    __syncthreads();  // b2: wmap^T ready

    // ---- T: TT[q][d] = (X wmap)[d][q], d-tiles {2w,2w+1} x 4 q-tiles ----
    {
      f32x4 tacc[2][4];
#pragma unroll
      for (int i = 0; i < 2; ++i)
#pragma unroll
        for (int j = 0; j < 4; ++j) tacc[i][j] = (f32x4){0.f, 0.f, 0.f, 0.f};
#pragma unroll
      for (int kk = 0; kk < 2; ++kk) {
        bf16x8 bw[4];
#pragma unroll
        for (int j = 0; j < 4; ++j)
          bw[j] = *(const bf16x8*)(&StB[(j * 16 + l16) * 72 + kk * 32 + quad * 8]);
#pragma unroll
        for (int i = 0; i < 2; ++i)
#pragma unroll
          for (int j = 0; j < 4; ++j)
            tacc[i][j] = __builtin_amdgcn_mfma_f32_16x16x32_bf16(xfr[i][kk], bw[j], tacc[i][j], 0, 0, 0);
      }
#pragma unroll
      for (int i = 0; i < 2; ++i)
#pragma unroll
        for (int j = 0; j < 4; ++j)
          *(ushort4*)(&TT[(j * 16 + l16) * XP3 + (wave * 2 + i) * 16 + quad * 4]) =
              pack4(tacc[i][j]);
    }
    __syncthreads();  // b3: TT ready

    // ---- phase 4: yac[o][q] += TT . Wov_h; o-tiles {2w,2w+1} ----
    {
      const ushort_t* wb = Wov3 + h * 256 + quad * 8;
#pragma unroll
      for (int kk = 0; kk < 8; ++kk) {
        bf16x8 at[4];
#pragma unroll
        for (int j = 0; j < 4; ++j)
          at[j] = *(const bf16x8*)(&TT[(j * 16 + l16) * XP3 + kk * 32 + quad * 8]);
#pragma unroll
        for (int i = 0; i < 2; ++i) {
          bf16x8 bwv = *(const bf16x8*)(wb + (size_t)((wave * 2 + i) * 16 + l16) * 2048 + kk * 32);
#pragma unroll
          for (int j = 0; j < 4; ++j)
            yac[i][j] = __builtin_amdgcn_mfma_f32_16x16x32_bf16(at[j], bwv, yac[i][j], 0, 0, 0);
        }
      }
    }
  }

  // ---- epilogue: out[n][o][pos(q)] = yac + cvec ----
  float* obase = out + (size_t)n * 256 * 3136;
#pragma unroll
  for (int i = 0; i < 2; ++i) {
    const int o = (wave * 2 + i) * 16 + l16;
    const float cv = cvec[o];
#pragma unroll
    for (int j = 0; j < 4; ++j) {
#pragma unroll
      for (int r = 0; r < 4; ++r) {
        int qv = j * 16 + quad * 4 + r;
        if (qv < 49) {
          int pos = tmap(qv, gi, gj);
          obase[(size_t)o * 3136 + pos] = yac[i][j][r] + cv;
        }
      }
    }
  }
}

extern "C" void kernel_launch(void* const* d_in, const int* in_sizes, int n_in,
                              void* d_out, int out_size, void* d_ws, size_t ws_size,
                              hipStream_t stream) {
  (void)in_sizes; (void)n_in; (void)out_size; (void)ws_size;
  const float* X  = (const float*)d_in[0];
  const float* Wk = (const float*)d_in[1];
  const float* bk = (const float*)d_in[2];
  const float* Wq = (const float*)d_in[3];
  const float* bq = (const float*)d_in[4];
  const float* Wv = (const float*)d_in[5];
  const float* bv = (const float*)d_in[6];
  const float* Wo = (const float*)d_in[7];
  const float* bo = (const float*)d_in[8];
  const float* rc = (const float*)d_in[9];

  ushort_t* MT    = (ushort_t*)d_ws;                       // 8*3200*2176 u16
  ushort_t* Xroll = MT + (size_t)8 * TROWS * MSTR;         // 8*3200*256 u16
  ushort_t* Aext  = Xroll + (size_t)8 * TROWS * 256;       // 2176*256 u16
  ushort_t* Wov3  = Aext + 2176 * 256;                     // 256*2048 u16
  float* fbase = (float*)(Wov3 + 256 * 2048);
  float* cvec  = fbase;         // 256 f32
  float* relL2 = fbase + 256;   // 8*169 f32
  float* out = (float*)d_out;

  k_prep <<<dim3(1290), dim3(256), 0, stream>>>(Wk, Wq, Wo, Wv, bk, bq, bv, bo, rc,
                                                Aext, Wov3, cvec, relL2);
  k_conv <<<dim3(8 * 57), dim3(256), 0, stream>>>(X, Xroll);
  k_gemm1<<<dim3(8 * 425), dim3(256), 0, stream>>>(Xroll, Aext, MT);
  k_attn3<<<dim3(8 * 64), dim3(512), 0, stream>>>(Xroll, MT, Wov3, relL2, cvec, out);
}